// Round 1
// baseline (956.836 us; speedup 1.0000x reference)
//
#include <hip/hip_runtime.h>

#define NNODES 2000
#define BATCH  64
#define DIM    256
#define GRID   256
#define BLOCK  256

typedef __attribute__((ext_vector_type(8))) short  v8s;
typedef __attribute__((ext_vector_type(8))) __bf16 v8bf;
typedef __attribute__((ext_vector_type(4))) float  v4f;
typedef __attribute__((ext_vector_type(4))) int    v4i;

__device__ __forceinline__ short f2bf(float f) {
  unsigned u = __builtin_bit_cast(unsigned, f);
  u += 0x7FFFu + ((u >> 16) & 1u);            // RNE
  return (short)(u >> 16);
}
__device__ __forceinline__ float bf2f(short s) {
  unsigned u = ((unsigned)(unsigned short)s) << 16;
  return __builtin_bit_cast(float, u);
}
__device__ __forceinline__ v4f mfma16(v8s a, v8s b, v4f c) {
  return __builtin_amdgcn_mfma_f32_16x16x32_bf16(
      __builtin_bit_cast(v8bf, a), __builtin_bit_cast(v8bf, b), c, 0, 0, 0);
}
__device__ __forceinline__ float sigmoidf(float x) {
  return __builtin_amdgcn_rcpf(1.0f + __builtin_amdgcn_exp2f(-1.4426950408889634f * x));
}

// Prep: Wt_in[j][k] = bf16(W_in[k][j]) (256x256);
//       Wt_inner[j][k] = bf16(k<256 ? W_inner[k][j]+W_inner[k+256][j] : W_inner[k+256][j]) (256x512);
//       done[] = 0.
__global__ void prep_kernel(const float* __restrict__ W_in, const float* __restrict__ W_inner,
                            short* __restrict__ Wt_in, short* __restrict__ Wt_inner,
                            int* __restrict__ done) {
  int idx = blockIdx.x * blockDim.x + threadIdx.x;
  int stride = gridDim.x * blockDim.x;
  for (int i = idx; i < 256 * 256; i += stride) {
    int j = i >> 8, k = i & 255;
    Wt_in[j * 256 + k] = f2bf(W_in[k * 256 + j]);
  }
  for (int i = idx; i < 256 * 512; i += stride) {
    int j = i >> 9, k = i & 511;
    float v = W_inner[(k + 256) * 256 + j];
    if (k < 256) v += W_inner[k * 256 + j];
    Wt_inner[j * 512 + k] = f2bf(v);
  }
  for (int i = idx; i < NNODES; i += stride) done[i] = 0;
}

// Dataflow tree evaluation. Children indices > parent index, blocks walk nodes in
// descending order => the highest-index unfinished node is always ready => no deadlock
// (all blocks co-resident via cooperative launch).
__launch_bounds__(BLOCK, 1)
__global__ void tree_kernel(const int* __restrict__ structure, const float* __restrict__ features,
                            const float* __restrict__ b_in, const float* __restrict__ b_inner,
                            const short* __restrict__ Wt_in, const short* __restrict__ Wt_inner,
                            short* __restrict__ state, int* done, float* __restrict__ out) {
  __shared__ short Xs[32][520];   // 32 batch rows x K(<=512), pad->520: 16B-aligned rows, 2-way-bank only
  __shared__ short Ws[256][40];   // 256 j rows x 32 k, pad->40: 16B-aligned rows

  const int tid  = threadIdx.x;
  const int wave = tid >> 6;
  const int lane = tid & 63;
  const int ln15 = lane & 15;
  const int quad = lane >> 4;

  for (int node = NNODES - 1 - (int)blockIdx.x; node >= 0; node -= GRID) {
    const int s = structure[2 * node];
    const int e = structure[2 * node + 1];
    const bool leaf = (s < 0);
    const int K = leaf ? 256 : 512;
    const short* __restrict__ W = leaf ? Wt_in : Wt_inner;
    const float* __restrict__ bias = leaf ? b_in : b_inner;

    if (!leaf) {
      if (tid == 0) {
        for (int c = s; c < e; ++c) {
          int guard = 0;
          while (atomicAdd(&done[c], 0) == 0 && guard < (1 << 22)) { __builtin_amdgcn_s_sleep(4); ++guard; }
        }
      }
      __syncthreads();
      __threadfence();   // acquire: invalidate L1, see producer's state stores (cross-XCD)
    }

    for (int half = 0; half < 2; ++half) {
      __syncthreads();   // prior consumers of Xs/Ws are done

      // ---- build Xs (bf16) for batches [half*32, half*32+32) ----
      {
        const int bl = tid >> 3;            // 0..31
        const int b  = half * 32 + bl;
        const int d0 = (tid & 7) * 32;
        const float* __restrict__ fp = features + ((size_t)b * NNODES + node) * DIM;
        if (leaf) {
          #pragma unroll
          for (int d = 0; d < 32; d += 4) {
            const float4 f = *(const float4*)(fp + d0 + d);
            short4 o; o.x = f2bf(f.x); o.y = f2bf(f.y); o.z = f2bf(f.z); o.w = f2bf(f.w);
            *(short4*)&Xs[bl][d0 + d] = o;
          }
        } else {
          const float inv = 1.0f / (float)(e - s + 1);
          #pragma unroll
          for (int d = 0; d < 32; d += 4) {
            const float4 f = *(const float4*)(fp + d0 + d);
            float sm0 = f.x, sm1 = f.y, sm2 = f.z, sm3 = f.w;
            float mn0 = f.x, mn1 = f.y, mn2 = f.z, mn3 = f.w;
            for (int c = s; c < e; ++c) {
              const short4 cv = *(const short4*)(state + ((size_t)c * BATCH + b) * DIM + d0 + d);
              float v0 = bf2f(cv.x), v1 = bf2f(cv.y), v2 = bf2f(cv.z), v3 = bf2f(cv.w);
              sm0 += v0; sm1 += v1; sm2 += v2; sm3 += v3;
              mn0 = fminf(mn0, v0); mn1 = fminf(mn1, v1); mn2 = fminf(mn2, v2); mn3 = fminf(mn3, v3);
            }
            short4 om; om.x = f2bf(sm0 * inv); om.y = f2bf(sm1 * inv); om.z = f2bf(sm2 * inv); om.w = f2bf(sm3 * inv);
            *(short4*)&Xs[bl][d0 + d] = om;                 // c_mean -> k in [0,256)
            short4 on; on.x = f2bf(mn0); on.y = f2bf(mn1); on.z = f2bf(mn2); on.w = f2bf(mn3);
            *(short4*)&Xs[bl][256 + d0 + d] = on;           // c_min  -> k in [256,512)
          }
        }
      }

      // ---- GEMM: [32 x K] @ Wt^T -> [32 x 256], MFMA 16x16x32 bf16 ----
      v4f acc[2][4];
      #pragma unroll
      for (int mt = 0; mt < 2; ++mt)
        #pragma unroll
        for (int nt = 0; nt < 4; ++nt) acc[mt][nt] = v4f{0.0f, 0.0f, 0.0f, 0.0f};

      const int nkc = K >> 5;
      for (int kc = 0; kc < nkc; ++kc) {
        __syncthreads();
        // stage Wt[j][kc*32 .. +32) -> Ws  (coalesced: 4 lanes cover one 64B row-chunk)
        #pragma unroll
        for (int p = 0; p < 4; ++p) {
          const int row = p * 64 + (tid >> 2);
          const int ck  = (tid & 3) * 8;
          *(v4i*)&Ws[row][ck] = *(const v4i*)(W + (size_t)row * K + kc * 32 + ck);
        }
        __syncthreads();
        v8s af[2], bfr[4];
        #pragma unroll
        for (int mt = 0; mt < 2; ++mt)
          af[mt] = *(const v8s*)&Xs[mt * 16 + ln15][kc * 32 + quad * 8];
        #pragma unroll
        for (int nt = 0; nt < 4; ++nt)
          bfr[nt] = *(const v8s*)&Ws[wave * 64 + nt * 16 + ln15][quad * 8];
        #pragma unroll
        for (int mt = 0; mt < 2; ++mt)
          #pragma unroll
          for (int nt = 0; nt < 4; ++nt)
            acc[mt][nt] = mfma16(af[mt], bfr[nt], acc[mt][nt]);
      }

      // ---- epilogue: bias + sigmoid, store state (bf16) and root output (fp32) ----
      #pragma unroll
      for (int mt = 0; mt < 2; ++mt) {
        #pragma unroll
        for (int nt = 0; nt < 4; ++nt) {
          const int j = wave * 64 + nt * 16 + ln15;
          const float bs = bias[j];
          #pragma unroll
          for (int r = 0; r < 4; ++r) {
            const int bb = half * 32 + mt * 16 + quad * 4 + r;
            const float v = sigmoidf(acc[mt][nt][r] + bs);
            state[((size_t)node * BATCH + bb) * DIM + j] = f2bf(v);
            if (node == 0) out[bb * DIM + j] = v;
          }
        }
      }
    } // half

    __threadfence();      // release: make state stores device-visible
    __syncthreads();
    if (tid == 0) atomicExch(&done[node], 1);
  }
}

extern "C" void kernel_launch(void* const* d_in, const int* in_sizes, int n_in,
                              void* d_out, int out_size, void* d_ws, size_t ws_size,
                              hipStream_t stream) {
  const int*   structure = (const int*)d_in[0];
  const float* features  = (const float*)d_in[1];
  const float* W_in      = (const float*)d_in[2];
  const float* b_in      = (const float*)d_in[3];
  const float* W_inner   = (const float*)d_in[4];
  const float* b_inner   = (const float*)d_in[5];
  float* out = (float*)d_out;

  char* ws = (char*)d_ws;
  short* state = (short*)ws;                                   // 2000*64*256*2 = 65,536,000 B
  size_t off = (size_t)NNODES * BATCH * DIM * 2;
  short* Wt_in = (short*)(ws + off);    off += 256 * 256 * 2;  // 131,072 B
  short* Wt_inner = (short*)(ws + off); off += 512 * 256 * 2;  // 262,144 B
  int* done = (int*)(ws + off);                                 // 8,000 B

  prep_kernel<<<dim3(256), dim3(256), 0, stream>>>(W_in, W_inner, Wt_in, Wt_inner, done);

  void* args[9];
  args[0] = (void*)&structure;
  args[1] = (void*)&features;
  args[2] = (void*)&b_in;
  args[3] = (void*)&b_inner;
  args[4] = (void*)&Wt_in;
  args[5] = (void*)&Wt_inner;
  args[6] = (void*)&state;
  args[7] = (void*)&done;
  args[8] = (void*)&out;
  hipLaunchCooperativeKernel((void*)tree_kernel, dim3(GRID), dim3(BLOCK), args, 0, stream);
}